// Round 1
// baseline (965.849 us; speedup 1.0000x reference)
//
#include <hip/hip_runtime.h>

#define T_TOK 8192
#define D_DIM 1024
#define E_NUM 32
#define K_TOP 4
#define CAP 1280
#define I_DIM 512

#define BM 128
#define BN 128
#define BK 32
#define LDA (BK + 8)   // pad 32->40 ushorts (80B row stride, keeps 16B alignment)

typedef float f32x4 __attribute__((ext_vector_type(4)));
typedef short s16x8 __attribute__((ext_vector_type(8)));

static __device__ __forceinline__ unsigned short f2bf(float f) {
    unsigned int u = __float_as_uint(f);
    unsigned int r = (u + 0x7fffu + ((u >> 16) & 1u)) >> 16;
    return (unsigned short)r;
}

// ---------------- router: logits = x @ router_w^T (fp32 exact) ----------------
__global__ __launch_bounds__(256) void router_kernel(
    const float* __restrict__ x, const float* __restrict__ rw,
    float* __restrict__ logits) {
    int t = (blockIdx.x * 256 + threadIdx.x) >> 6;   // one wave per token
    int lane = threadIdx.x & 63;
    const float* xr = x + (size_t)t * D_DIM;
    float xf[16];
#pragma unroll
    for (int j = 0; j < 16; ++j) xf[j] = xr[lane + 64 * j];
#pragma unroll 1
    for (int e = 0; e < E_NUM; ++e) {
        const float* wr = rw + (size_t)e * D_DIM;
        float acc = 0.f;
#pragma unroll
        for (int j = 0; j < 16; ++j) acc = fmaf(xf[j], wr[lane + 64 * j], acc);
#pragma unroll
        for (int off = 32; off; off >>= 1) acc += __shfl_xor(acc, off);
        if (lane == 0) logits[(size_t)t * E_NUM + e] = acc;
    }
}

// ------------- softmax + top-4 + renorm + slot assignment (wave/token) -------------
__global__ __launch_bounds__(256) void topk_kernel(
    const float* __restrict__ logits,
    int* __restrict__ counts, int* __restrict__ rowtok, float* __restrict__ rowcoef) {
    int t = (blockIdx.x * 256 + threadIdx.x) >> 6;
    int lane = threadIdx.x & 63;
    float v = -1e30f;
    if (lane < E_NUM) v = logits[(size_t)t * E_NUM + lane];
    float m = v;
#pragma unroll
    for (int off = 16; off; off >>= 1) m = fmaxf(m, __shfl_xor(m, off));
    float p = (lane < E_NUM) ? __expf(v - m) : 0.0f;
    float s = p;
#pragma unroll
    for (int off = 16; off; off >>= 1) s += __shfl_xor(s, off);
    p /= s;

    float cur = p;
    float wv[K_TOP];
    int sel[K_TOP];
#pragma unroll
    for (int k = 0; k < K_TOP; ++k) {
        float mv = cur;
        int mi = lane;
#pragma unroll
        for (int off = 16; off; off >>= 1) {
            float ov = __shfl_xor(mv, off);
            int oi = __shfl_xor(mi, off);
            if (ov > mv || (ov == mv && oi < mi)) { mv = ov; mi = oi; }
        }
        wv[k] = mv; sel[k] = mi;
        if (lane == mi) cur = -1.0f;   // remove winner (probs are >= 0)
    }
    if (lane == 0) {
        float inv = 1.0f / (wv[0] + wv[1] + wv[2] + wv[3]);
#pragma unroll
        for (int k = 0; k < K_TOP; ++k) {
            int slot = atomicAdd(&counts[sel[k]], 1);
            if (slot < CAP) {
                rowtok[sel[k] * CAP + slot] = t;
                rowcoef[sel[k] * CAP + slot] = wv[k] * inv;
            }
        }
    }
}

// ---------------- gate+up GEMM fused, h = silu(g)*u -> bf16 ws ----------------
__global__ __launch_bounds__(256) void gateup_kernel(
    const float* __restrict__ x,
    const float* __restrict__ gate_w, const float* __restrict__ up_w,
    const int* __restrict__ counts, const int* __restrict__ rowtok,
    unsigned short* __restrict__ h_ws) {
    int bid = blockIdx.x;
    int e = bid / ((CAP / BM) * (I_DIM / BN));
    int rem = bid % ((CAP / BM) * (I_DIM / BN));
    int mt = rem / (I_DIM / BN);
    int nt = rem % (I_DIM / BN);
    int n_e = counts[e]; if (n_e > CAP) n_e = CAP;
    if (mt * BM >= n_e) return;

    __shared__ unsigned short As[BM][LDA];
    __shared__ unsigned short Bg[BM][LDA];
    __shared__ unsigned short Bu[BM][LDA];
    __shared__ int toks[BM];

    int tid = threadIdx.x;
    if (tid < BM) {
        int r = mt * BM + tid;
        toks[tid] = (r < n_e) ? rowtok[e * CAP + r] : -1;
    }
    __syncthreads();

    int lane = tid & 63;
    int wv = tid >> 6;
    int wm = (wv >> 1) * 64;
    int wn = (wv & 1) * 64;

    f32x4 accg[4][4] = {};
    f32x4 accu[4][4] = {};

    const float* gbase = gate_w + ((size_t)e * I_DIM + nt * BN) * D_DIM;
    const float* ubase = up_w + ((size_t)e * I_DIM + nt * BN) * D_DIM;

    for (int kk = 0; kk < D_DIM; kk += BK) {
        // stage A (gathered x rows), fp32 -> bf16
#pragma unroll
        for (int it = 0; it < 4; ++it) {
            int idx = tid + it * 256;
            int row = idx >> 3;
            int col = (idx & 7) * 4;
            int tk = toks[row];
            float4 v = make_float4(0.f, 0.f, 0.f, 0.f);
            if (tk >= 0) v = *(const float4*)(x + (size_t)tk * D_DIM + kk + col);
            ushort4 b;
            b.x = f2bf(v.x); b.y = f2bf(v.y); b.z = f2bf(v.z); b.w = f2bf(v.w);
            *(ushort4*)&As[row][col] = b;
        }
        // stage Bg / Bu
#pragma unroll
        for (int it = 0; it < 4; ++it) {
            int idx = tid + it * 256;
            int row = idx >> 3;
            int col = (idx & 7) * 4;
            float4 g = *(const float4*)(gbase + (size_t)row * D_DIM + kk + col);
            ushort4 bg;
            bg.x = f2bf(g.x); bg.y = f2bf(g.y); bg.z = f2bf(g.z); bg.w = f2bf(g.w);
            *(ushort4*)&Bg[row][col] = bg;
            float4 u = *(const float4*)(ubase + (size_t)row * D_DIM + kk + col);
            ushort4 bu;
            bu.x = f2bf(u.x); bu.y = f2bf(u.y); bu.z = f2bf(u.z); bu.w = f2bf(u.w);
            *(ushort4*)&Bu[row][col] = bu;
        }
        __syncthreads();

        s16x8 af[4], bgf[4], buf[4];
#pragma unroll
        for (int mi = 0; mi < 4; ++mi)
            af[mi] = *(const s16x8*)&As[wm + mi * 16 + (lane & 15)][(lane >> 4) * 8];
#pragma unroll
        for (int ni = 0; ni < 4; ++ni) {
            bgf[ni] = *(const s16x8*)&Bg[wn + ni * 16 + (lane & 15)][(lane >> 4) * 8];
            buf[ni] = *(const s16x8*)&Bu[wn + ni * 16 + (lane & 15)][(lane >> 4) * 8];
        }
#pragma unroll
        for (int mi = 0; mi < 4; ++mi)
#pragma unroll
            for (int ni = 0; ni < 4; ++ni) {
                accg[mi][ni] = __builtin_amdgcn_mfma_f32_16x16x32_bf16(af[mi], bgf[ni], accg[mi][ni], 0, 0, 0);
                accu[mi][ni] = __builtin_amdgcn_mfma_f32_16x16x32_bf16(af[mi], buf[ni], accu[mi][ni], 0, 0, 0);
            }
        __syncthreads();
    }

    // epilogue: h = silu(g) * u, bf16 store
    int rq = (lane >> 4) * 4;
    int cq = lane & 15;
#pragma unroll
    for (int mi = 0; mi < 4; ++mi)
#pragma unroll
        for (int ni = 0; ni < 4; ++ni)
#pragma unroll
            for (int r = 0; r < 4; ++r) {
                int grow = mt * BM + wm + mi * 16 + rq + r;
                if (grow < n_e) {
                    float g = accg[mi][ni][r];
                    float hv = g / (1.0f + __expf(-g)) * accu[mi][ni][r];
                    int icol = nt * BN + wn + ni * 16 + cq;
                    h_ws[((size_t)e * CAP + grow) * I_DIM + icol] = f2bf(hv);
                }
            }
}

// ---------------- down GEMM + weighted atomic scatter-combine ----------------
__global__ __launch_bounds__(256) void down_kernel(
    const unsigned short* __restrict__ h_ws, const float* __restrict__ down_w,
    const int* __restrict__ counts, const int* __restrict__ rowtok,
    const float* __restrict__ rowcoef, float* __restrict__ out) {
    int bid = blockIdx.x;
    int e = bid / ((CAP / BM) * (D_DIM / BN));
    int rem = bid % ((CAP / BM) * (D_DIM / BN));
    int mt = rem / (D_DIM / BN);
    int nt = rem % (D_DIM / BN);
    int n_e = counts[e]; if (n_e > CAP) n_e = CAP;
    if (mt * BM >= n_e) return;

    __shared__ unsigned short As[BM][LDA];
    __shared__ unsigned short Bd[BM][LDA];
    __shared__ int toks[BM];
    __shared__ float coefs[BM];

    int tid = threadIdx.x;
    if (tid < BM) {
        int r = mt * BM + tid;
        toks[tid] = (r < n_e) ? rowtok[e * CAP + r] : 0;
        coefs[tid] = (r < n_e) ? rowcoef[e * CAP + r] : 0.f;
    }
    __syncthreads();

    int lane = tid & 63;
    int wv = tid >> 6;
    int wm = (wv >> 1) * 64;
    int wn = (wv & 1) * 64;

    f32x4 acc[4][4] = {};

    const unsigned short* abase = h_ws + ((size_t)e * CAP + mt * BM) * I_DIM;
    const float* bbase = down_w + ((size_t)e * D_DIM + nt * BN) * I_DIM;

    for (int kk = 0; kk < I_DIM; kk += BK) {
        // stage A from bf16 h (16B vector loads)
#pragma unroll
        for (int it = 0; it < 2; ++it) {
            int idx = tid + it * 256;
            int row = idx >> 2;
            int col = (idx & 3) * 8;
            s16x8 v = {};
            if (mt * BM + row < n_e) v = *(const s16x8*)(abase + (size_t)row * I_DIM + kk + col);
            *(s16x8*)&As[row][col] = v;
        }
        // stage B (down_w rows), fp32 -> bf16
#pragma unroll
        for (int it = 0; it < 4; ++it) {
            int idx = tid + it * 256;
            int row = idx >> 3;
            int col = (idx & 7) * 4;
            float4 b = *(const float4*)(bbase + (size_t)row * I_DIM + kk + col);
            ushort4 bb;
            bb.x = f2bf(b.x); bb.y = f2bf(b.y); bb.z = f2bf(b.z); bb.w = f2bf(b.w);
            *(ushort4*)&Bd[row][col] = bb;
        }
        __syncthreads();

        s16x8 af[4], bf[4];
#pragma unroll
        for (int mi = 0; mi < 4; ++mi)
            af[mi] = *(const s16x8*)&As[wm + mi * 16 + (lane & 15)][(lane >> 4) * 8];
#pragma unroll
        for (int ni = 0; ni < 4; ++ni)
            bf[ni] = *(const s16x8*)&Bd[wn + ni * 16 + (lane & 15)][(lane >> 4) * 8];
#pragma unroll
        for (int mi = 0; mi < 4; ++mi)
#pragma unroll
            for (int ni = 0; ni < 4; ++ni)
                acc[mi][ni] = __builtin_amdgcn_mfma_f32_16x16x32_bf16(af[mi], bf[ni], acc[mi][ni], 0, 0, 0);
        __syncthreads();
    }

    int rq = (lane >> 4) * 4;
    int cq = lane & 15;
#pragma unroll
    for (int mi = 0; mi < 4; ++mi)
#pragma unroll
        for (int ni = 0; ni < 4; ++ni)
#pragma unroll
            for (int r = 0; r < 4; ++r) {
                int lrow = wm + mi * 16 + rq + r;
                int grow = mt * BM + lrow;
                if (grow < n_e) {
                    int t = toks[lrow];
                    float c = coefs[lrow];
                    int dcol = nt * BN + wn + ni * 16 + cq;
                    atomicAdd(&out[(size_t)t * D_DIM + dcol], acc[mi][ni][r] * c);
                }
            }
}

extern "C" void kernel_launch(void* const* d_in, const int* in_sizes, int n_in,
                              void* d_out, int out_size, void* d_ws, size_t ws_size,
                              hipStream_t stream) {
    const float* x  = (const float*)d_in[0];
    const float* rw = (const float*)d_in[1];
    const float* gw = (const float*)d_in[2];
    const float* uw = (const float*)d_in[3];
    const float* dw = (const float*)d_in[4];
    float* out = (float*)d_out;
    float* logits = out + (size_t)T_TOK * D_DIM;

    char* ws = (char*)d_ws;
    unsigned short* h_ws = (unsigned short*)ws;
    size_t off = (size_t)E_NUM * CAP * I_DIM * 2;           // 41,943,040 B
    int* counts = (int*)(ws + off); off += 256;
    int* rowtok = (int*)(ws + off); off += (size_t)E_NUM * CAP * 4;
    float* rowcoef = (float*)(ws + off); off += (size_t)E_NUM * CAP * 4;

    hipMemsetAsync(d_out, 0, (size_t)T_TOK * D_DIM * 4, stream);  // zero `final` region
    hipMemsetAsync(counts, 0, E_NUM * 4, stream);

    router_kernel<<<T_TOK / 4, 256, 0, stream>>>(x, rw, logits);
    topk_kernel<<<T_TOK / 4, 256, 0, stream>>>(logits, counts, rowtok, rowcoef);
    gateup_kernel<<<E_NUM * (CAP / BM) * (I_DIM / BN), 256, 0, stream>>>(x, gw, uw, counts, rowtok, h_ws);
    down_kernel<<<E_NUM * (CAP / BM) * (D_DIM / BN), 256, 0, stream>>>(h_ws, dw, counts, rowtok, rowcoef, out);
}

// Round 2
// 795.602 us; speedup vs baseline: 1.2140x; 1.2140x over previous
//
#include <hip/hip_runtime.h>

#define T_TOK 8192
#define D_DIM 1024
#define E_NUM 32
#define K_TOP 4
#define CAP 1280
#define I_DIM 512

#define BM 128
#define BN 128
#define BK 32

typedef float f32x4 __attribute__((ext_vector_type(4)));
typedef short s16x8 __attribute__((ext_vector_type(8)));

static __device__ __forceinline__ unsigned short f2bf(float f) {
    unsigned int u = __float_as_uint(f);
    unsigned int r = (u + 0x7fffu + ((u >> 16) & 1u)) >> 16;
    return (unsigned short)r;
}

// async 16B global->LDS (dest = wave-uniform base + lane*16)
static __device__ __forceinline__ void gload16(const unsigned short* g, unsigned short* l) {
    __builtin_amdgcn_global_load_lds(
        (const __attribute__((address_space(1))) unsigned int*)g,
        (__attribute__((address_space(3))) unsigned int*)l,
        16, 0, 0);
}

// ---------------- fp32 -> bf16 pre-convert (x, gate_w, up_w, down_w) ----------------
#define X_F4  2097152L
#define GW_F4 4194304L
__global__ __launch_bounds__(256) void cvt_kernel(
    const float* __restrict__ x, const float* __restrict__ gw,
    const float* __restrict__ uw, const float* __restrict__ dw,
    unsigned short* __restrict__ xbf, unsigned short* __restrict__ gbf,
    unsigned short* __restrict__ ubf, unsigned short* __restrict__ dbf) {
    long i = (long)blockIdx.x * 256 + threadIdx.x;   // float4 index
    const float* src; unsigned short* dst; long off;
    if (i < X_F4)                { src = x;  dst = xbf; off = i; }
    else if (i < X_F4 + GW_F4)   { src = gw; dst = gbf; off = i - X_F4; }
    else if (i < X_F4 + 2*GW_F4) { src = uw; dst = ubf; off = i - X_F4 - GW_F4; }
    else                         { src = dw; dst = dbf; off = i - X_F4 - 2*GW_F4; }
    float4 v = ((const float4*)src)[off];
    ushort4 b;
    b.x = f2bf(v.x); b.y = f2bf(v.y); b.z = f2bf(v.z); b.w = f2bf(v.w);
    ((ushort4*)dst)[off] = b;
}

// ---------------- router: logits = x @ router_w^T (fp32 exact) ----------------
__global__ __launch_bounds__(256) void router_kernel(
    const float* __restrict__ x, const float* __restrict__ rw,
    float* __restrict__ logits) {
    int t = (blockIdx.x * 256 + threadIdx.x) >> 6;   // one wave per token
    int lane = threadIdx.x & 63;
    const float* xr = x + (size_t)t * D_DIM;
    float xf[16];
#pragma unroll
    for (int j = 0; j < 16; ++j) xf[j] = xr[lane + 64 * j];
#pragma unroll 1
    for (int e = 0; e < E_NUM; ++e) {
        const float* wr = rw + (size_t)e * D_DIM;
        float acc = 0.f;
#pragma unroll
        for (int j = 0; j < 16; ++j) acc = fmaf(xf[j], wr[lane + 64 * j], acc);
#pragma unroll
        for (int off = 32; off; off >>= 1) acc += __shfl_xor(acc, off);
        if (lane == 0) logits[(size_t)t * E_NUM + e] = acc;
    }
}

// ------------- softmax + top-4 + renorm + slot assignment (wave/token) -------------
__global__ __launch_bounds__(256) void topk_kernel(
    const float* __restrict__ logits,
    int* __restrict__ counts, int* __restrict__ rowtok, float* __restrict__ rowcoef) {
    int t = (blockIdx.x * 256 + threadIdx.x) >> 6;
    int lane = threadIdx.x & 63;
    float v = -1e30f;
    if (lane < E_NUM) v = logits[(size_t)t * E_NUM + lane];
    float m = v;
#pragma unroll
    for (int off = 16; off; off >>= 1) m = fmaxf(m, __shfl_xor(m, off));
    float p = (lane < E_NUM) ? __expf(v - m) : 0.0f;
    float s = p;
#pragma unroll
    for (int off = 16; off; off >>= 1) s += __shfl_xor(s, off);
    p /= s;

    float cur = p;
    float wv[K_TOP];
    int sel[K_TOP];
#pragma unroll
    for (int k = 0; k < K_TOP; ++k) {
        float mv = cur;
        int mi = lane;
#pragma unroll
        for (int off = 16; off; off >>= 1) {
            float ov = __shfl_xor(mv, off);
            int oi = __shfl_xor(mi, off);
            if (ov > mv || (ov == mv && oi < mi)) { mv = ov; mi = oi; }
        }
        wv[k] = mv; sel[k] = mi;
        if (lane == mi) cur = -1.0f;
    }
    if (lane == 0) {
        float inv = 1.0f / (wv[0] + wv[1] + wv[2] + wv[3]);
#pragma unroll
        for (int k = 0; k < K_TOP; ++k) {
            int slot = atomicAdd(&counts[sel[k]], 1);
            if (slot < CAP) {
                rowtok[sel[k] * CAP + slot] = t;
                rowcoef[sel[k] * CAP + slot] = wv[k] * inv;
            }
        }
    }
}

// ---------------- gate+up GEMM fused (bf16, global_load_lds), h = silu(g)*u ----------------
__global__ __launch_bounds__(256) void gateup_kernel(
    const unsigned short* __restrict__ xbf,
    const unsigned short* __restrict__ gbf, const unsigned short* __restrict__ ubf,
    const int* __restrict__ counts, const int* __restrict__ rowtok,
    unsigned short* __restrict__ h_ws) {
    int bid = blockIdx.x;
    int e = bid / ((CAP / BM) * (I_DIM / BN));
    int rem = bid % ((CAP / BM) * (I_DIM / BN));
    int mt = rem / (I_DIM / BN);
    int nt = rem % (I_DIM / BN);
    int n_e = counts[e]; if (n_e > CAP) n_e = CAP;
    if (mt * BM >= n_e) return;   // implies n_e >= 1 below

    __shared__ unsigned short As[BM * BK];   // [row][k], 64B rows, unpadded
    __shared__ unsigned short Bg[BM * BK];
    __shared__ unsigned short Bu[BM * BK];
    __shared__ int toks[BM];

    int tid = threadIdx.x, lane = tid & 63, wv = tid >> 6;
    if (tid < BM) {
        int r = mt * BM + tid;
        toks[tid] = (r < n_e) ? rowtok[e * CAP + r] : rowtok[e * CAP];  // clamp to a valid token
    }
    __syncthreads();

    // staging geometry: issue i of wave wv covers rows (wv*2+i)*16 + lane/4, col (lane&3)*8
    int rA0 = (wv * 2 + 0) * 16 + (lane >> 2);
    int rA1 = rA0 + 16;
    int cst = (lane & 3) * 8;
    const unsigned short* gaA0 = xbf + (size_t)toks[rA0] * D_DIM + cst;
    const unsigned short* gaA1 = xbf + (size_t)toks[rA1] * D_DIM + cst;
    const unsigned short* gaG0 = gbf + ((size_t)e * I_DIM + nt * BN + rA0) * D_DIM + cst;
    const unsigned short* gaG1 = gbf + ((size_t)e * I_DIM + nt * BN + rA1) * D_DIM + cst;
    const unsigned short* gaU0 = ubf + ((size_t)e * I_DIM + nt * BN + rA0) * D_DIM + cst;
    const unsigned short* gaU1 = ubf + ((size_t)e * I_DIM + nt * BN + rA1) * D_DIM + cst;
    unsigned short* lA0 = &As[(wv * 2 + 0) * 512];
    unsigned short* lA1 = &As[(wv * 2 + 1) * 512];
    unsigned short* lG0 = &Bg[(wv * 2 + 0) * 512];
    unsigned short* lG1 = &Bg[(wv * 2 + 1) * 512];
    unsigned short* lU0 = &Bu[(wv * 2 + 0) * 512];
    unsigned short* lU1 = &Bu[(wv * 2 + 1) * 512];

    int wm = (wv >> 1) * 64;
    int wn = (wv & 1) * 64;

    f32x4 accg[4][4] = {};
    f32x4 accu[4][4] = {};

    for (int kk = 0; kk < D_DIM; kk += BK) {
        gload16(gaA0 + kk, lA0);
        gload16(gaA1 + kk, lA1);
        gload16(gaG0 + kk, lG0);
        gload16(gaG1 + kk, lG1);
        gload16(gaU0 + kk, lU0);
        gload16(gaU1 + kk, lU1);
        __syncthreads();

        s16x8 af[4], bgf[4], buf[4];
#pragma unroll
        for (int mi = 0; mi < 4; ++mi)
            af[mi] = *(const s16x8*)&As[(wm + mi * 16 + (lane & 15)) * BK + (lane >> 4) * 8];
#pragma unroll
        for (int ni = 0; ni < 4; ++ni) {
            bgf[ni] = *(const s16x8*)&Bg[(wn + ni * 16 + (lane & 15)) * BK + (lane >> 4) * 8];
            buf[ni] = *(const s16x8*)&Bu[(wn + ni * 16 + (lane & 15)) * BK + (lane >> 4) * 8];
        }
#pragma unroll
        for (int mi = 0; mi < 4; ++mi)
#pragma unroll
            for (int ni = 0; ni < 4; ++ni) {
                accg[mi][ni] = __builtin_amdgcn_mfma_f32_16x16x32_bf16(af[mi], bgf[ni], accg[mi][ni], 0, 0, 0);
                accu[mi][ni] = __builtin_amdgcn_mfma_f32_16x16x32_bf16(af[mi], buf[ni], accu[mi][ni], 0, 0, 0);
            }
        __syncthreads();
    }

    int rq = (lane >> 4) * 4;
    int cq = lane & 15;
#pragma unroll
    for (int mi = 0; mi < 4; ++mi)
#pragma unroll
        for (int ni = 0; ni < 4; ++ni)
#pragma unroll
            for (int r = 0; r < 4; ++r) {
                int grow = mt * BM + wm + mi * 16 + rq + r;
                if (grow < n_e) {
                    float g = accg[mi][ni][r];
                    float hv = g / (1.0f + __expf(-g)) * accu[mi][ni][r];
                    int icol = nt * BN + wn + ni * 16 + cq;
                    h_ws[((size_t)e * CAP + grow) * I_DIM + icol] = f2bf(hv);
                }
            }
}

// ---------------- down GEMM (bf16, global_load_lds) + weighted atomic combine ----------------
__global__ __launch_bounds__(256) void down_kernel(
    const unsigned short* __restrict__ h_ws, const unsigned short* __restrict__ dbf,
    const int* __restrict__ counts, const int* __restrict__ rowtok,
    const float* __restrict__ rowcoef, float* __restrict__ out) {
    int bid = blockIdx.x;
    int e = bid / ((CAP / BM) * (D_DIM / BN));
    int rem = bid % ((CAP / BM) * (D_DIM / BN));
    int mt = rem / (D_DIM / BN);
    int nt = rem % (D_DIM / BN);
    int n_e = counts[e]; if (n_e > CAP) n_e = CAP;
    if (mt * BM >= n_e) return;

    __shared__ unsigned short As[BM * BK];
    __shared__ unsigned short Bd[BM * BK];
    __shared__ int toks[BM];
    __shared__ float coefs[BM];

    int tid = threadIdx.x, lane = tid & 63, wv = tid >> 6;
    if (tid < BM) {
        int r = mt * BM + tid;
        toks[tid] = (r < n_e) ? rowtok[e * CAP + r] : 0;
        coefs[tid] = (r < n_e) ? rowcoef[e * CAP + r] : 0.f;
    }
    __syncthreads();

    int rA0 = (wv * 2 + 0) * 16 + (lane >> 2);
    int rA1 = rA0 + 16;
    int cst = (lane & 3) * 8;
    const unsigned short* gaA0 = h_ws + ((size_t)e * CAP + mt * BM + rA0) * I_DIM + cst;
    const unsigned short* gaA1 = h_ws + ((size_t)e * CAP + mt * BM + rA1) * I_DIM + cst;
    const unsigned short* gaB0 = dbf + ((size_t)e * D_DIM + nt * BN + rA0) * I_DIM + cst;
    const unsigned short* gaB1 = dbf + ((size_t)e * D_DIM + nt * BN + rA1) * I_DIM + cst;
    unsigned short* lA0 = &As[(wv * 2 + 0) * 512];
    unsigned short* lA1 = &As[(wv * 2 + 1) * 512];
    unsigned short* lB0 = &Bd[(wv * 2 + 0) * 512];
    unsigned short* lB1 = &Bd[(wv * 2 + 1) * 512];

    int wm = (wv >> 1) * 64;
    int wn = (wv & 1) * 64;

    f32x4 acc[4][4] = {};

    for (int kk = 0; kk < I_DIM; kk += BK) {
        gload16(gaA0 + kk, lA0);
        gload16(gaA1 + kk, lA1);
        gload16(gaB0 + kk, lB0);
        gload16(gaB1 + kk, lB1);
        __syncthreads();

        s16x8 af[4], bf[4];
#pragma unroll
        for (int mi = 0; mi < 4; ++mi)
            af[mi] = *(const s16x8*)&As[(wm + mi * 16 + (lane & 15)) * BK + (lane >> 4) * 8];
#pragma unroll
        for (int ni = 0; ni < 4; ++ni)
            bf[ni] = *(const s16x8*)&Bd[(wn + ni * 16 + (lane & 15)) * BK + (lane >> 4) * 8];
#pragma unroll
        for (int mi = 0; mi < 4; ++mi)
#pragma unroll
            for (int ni = 0; ni < 4; ++ni)
                acc[mi][ni] = __builtin_amdgcn_mfma_f32_16x16x32_bf16(af[mi], bf[ni], acc[mi][ni], 0, 0, 0);
        __syncthreads();
    }

    int rq = (lane >> 4) * 4;
    int cq = lane & 15;
#pragma unroll
    for (int mi = 0; mi < 4; ++mi)
#pragma unroll
        for (int ni = 0; ni < 4; ++ni)
#pragma unroll
            for (int r = 0; r < 4; ++r) {
                int lrow = wm + mi * 16 + rq + r;
                int grow = mt * BM + lrow;
                if (grow < n_e) {
                    int t = toks[lrow];
                    float c = coefs[lrow];
                    int dcol = nt * BN + wn + ni * 16 + cq;
                    atomicAdd(&out[(size_t)t * D_DIM + dcol], acc[mi][ni][r] * c);
                }
            }
}

extern "C" void kernel_launch(void* const* d_in, const int* in_sizes, int n_in,
                              void* d_out, int out_size, void* d_ws, size_t ws_size,
                              hipStream_t stream) {
    const float* x  = (const float*)d_in[0];
    const float* rw = (const float*)d_in[1];
    const float* gw = (const float*)d_in[2];
    const float* uw = (const float*)d_in[3];
    const float* dw = (const float*)d_in[4];
    float* out = (float*)d_out;
    float* logits = out + (size_t)T_TOK * D_DIM;

    char* ws = (char*)d_ws;
    size_t off = 0;
    unsigned short* xbf = (unsigned short*)(ws + off); off += (size_t)T_TOK * D_DIM * 2;          // 16.78 MB
    unsigned short* gbf = (unsigned short*)(ws + off); off += (size_t)E_NUM * I_DIM * D_DIM * 2;  // 33.55 MB
    unsigned short* ubf = (unsigned short*)(ws + off); off += (size_t)E_NUM * I_DIM * D_DIM * 2;  // 33.55 MB
    unsigned short* dbf = (unsigned short*)(ws + off); off += (size_t)E_NUM * D_DIM * I_DIM * 2;  // 33.55 MB
    unsigned short* h_ws = (unsigned short*)(ws + off); off += (size_t)E_NUM * CAP * I_DIM * 2;   // 41.94 MB
    int* counts = (int*)(ws + off); off += 256;
    int* rowtok = (int*)(ws + off); off += (size_t)E_NUM * CAP * 4;
    float* rowcoef = (float*)(ws + off); off += (size_t)E_NUM * CAP * 4;

    hipMemsetAsync(d_out, 0, (size_t)T_TOK * D_DIM * 4, stream);  // zero `final` region only
    hipMemsetAsync(counts, 0, E_NUM * 4, stream);

    cvt_kernel<<<(int)((X_F4 + 3 * GW_F4) / 256), 256, 0, stream>>>(x, gw, uw, dw, xbf, gbf, ubf, dbf);
    router_kernel<<<T_TOK / 4, 256, 0, stream>>>(x, rw, logits);
    topk_kernel<<<T_TOK / 4, 256, 0, stream>>>(logits, counts, rowtok, rowcoef);
    gateup_kernel<<<E_NUM * (CAP / BM) * (I_DIM / BN), 256, 0, stream>>>(xbf, gbf, ubf, counts, rowtok, h_ws);
    down_kernel<<<E_NUM * (CAP / BM) * (D_DIM / BN), 256, 0, stream>>>(h_ws, dbf, counts, rowtok, rowcoef, out);
}

// Round 3
// 740.194 us; speedup vs baseline: 1.3049x; 1.0749x over previous
//
#include <hip/hip_runtime.h>

#define T_TOK 8192
#define D_DIM 1024
#define E_NUM 32
#define K_TOP 4
#define CAP 1280
#define I_DIM 512

#define BM 128
#define BN 128
#define BK 32

typedef float f32x4 __attribute__((ext_vector_type(4)));
typedef short s16x8 __attribute__((ext_vector_type(8)));

static __device__ __forceinline__ unsigned short f2bf(float f) {
    unsigned int u = __float_as_uint(f);
    unsigned int r = (u + 0x7fffu + ((u >> 16) & 1u)) >> 16;
    return (unsigned short)r;
}
static __device__ __forceinline__ float bf2f(unsigned short s) {
    return __uint_as_float(((unsigned int)s) << 16);
}

// async 16B global->LDS (dest = wave-uniform base + lane*16)
static __device__ __forceinline__ void gload16(const unsigned short* g, unsigned short* l) {
    __builtin_amdgcn_global_load_lds(
        (const __attribute__((address_space(1))) unsigned int*)g,
        (__attribute__((address_space(3))) unsigned int*)l,
        16, 0, 0);
}

// ---------------- fp32 -> bf16 pre-convert (x, gate_w, up_w, down_w) ----------------
#define X_F4  2097152L
#define GW_F4 4194304L
__global__ __launch_bounds__(256) void cvt_kernel(
    const float* __restrict__ x, const float* __restrict__ gw,
    const float* __restrict__ uw, const float* __restrict__ dw,
    unsigned short* __restrict__ xbf, unsigned short* __restrict__ gbf,
    unsigned short* __restrict__ ubf, unsigned short* __restrict__ dbf) {
    long i = (long)blockIdx.x * 256 + threadIdx.x;   // float4 index
    const float* src; unsigned short* dst; long off;
    if (i < X_F4)                { src = x;  dst = xbf; off = i; }
    else if (i < X_F4 + GW_F4)   { src = gw; dst = gbf; off = i - X_F4; }
    else if (i < X_F4 + 2*GW_F4) { src = uw; dst = ubf; off = i - X_F4 - GW_F4; }
    else                         { src = dw; dst = dbf; off = i - X_F4 - 2*GW_F4; }
    float4 v = ((const float4*)src)[off];
    ushort4 b;
    b.x = f2bf(v.x); b.y = f2bf(v.y); b.z = f2bf(v.z); b.w = f2bf(v.w);
    ((ushort4*)dst)[off] = b;
}

// ---------------- router: logits = x @ router_w^T (fp32 exact) ----------------
__global__ __launch_bounds__(256) void router_kernel(
    const float* __restrict__ x, const float* __restrict__ rw,
    float* __restrict__ logits) {
    int t = (blockIdx.x * 256 + threadIdx.x) >> 6;   // one wave per token
    int lane = threadIdx.x & 63;
    const float* xr = x + (size_t)t * D_DIM;
    float xf[16];
#pragma unroll
    for (int j = 0; j < 16; ++j) xf[j] = xr[lane + 64 * j];
#pragma unroll 1
    for (int e = 0; e < E_NUM; ++e) {
        const float* wr = rw + (size_t)e * D_DIM;
        float acc = 0.f;
#pragma unroll
        for (int j = 0; j < 16; ++j) acc = fmaf(xf[j], wr[lane + 64 * j], acc);
#pragma unroll
        for (int off = 32; off; off >>= 1) acc += __shfl_xor(acc, off);
        if (lane == 0) logits[(size_t)t * E_NUM + e] = acc;
    }
}

// ------------- softmax + top-4 + renorm + slot assignment (wave/token) -------------
__global__ __launch_bounds__(256) void topk_kernel(
    const float* __restrict__ logits,
    int* __restrict__ counts, int* __restrict__ rowtok,
    int* __restrict__ tokslot, float* __restrict__ tokcoef) {
    int t = (blockIdx.x * 256 + threadIdx.x) >> 6;
    int lane = threadIdx.x & 63;
    float v = -1e30f;
    if (lane < E_NUM) v = logits[(size_t)t * E_NUM + lane];
    float m = v;
#pragma unroll
    for (int off = 16; off; off >>= 1) m = fmaxf(m, __shfl_xor(m, off));
    float p = (lane < E_NUM) ? __expf(v - m) : 0.0f;
    float s = p;
#pragma unroll
    for (int off = 16; off; off >>= 1) s += __shfl_xor(s, off);
    p /= s;

    float cur = p;
    float wv[K_TOP];
    int sel[K_TOP];
#pragma unroll
    for (int k = 0; k < K_TOP; ++k) {
        float mv = cur;
        int mi = lane;
#pragma unroll
        for (int off = 16; off; off >>= 1) {
            float ov = __shfl_xor(mv, off);
            int oi = __shfl_xor(mi, off);
            if (ov > mv || (ov == mv && oi < mi)) { mv = ov; mi = oi; }
        }
        wv[k] = mv; sel[k] = mi;
        if (lane == mi) cur = -1.0f;
    }
    if (lane == 0) {
        float inv = 1.0f / (wv[0] + wv[1] + wv[2] + wv[3]);
#pragma unroll
        for (int k = 0; k < K_TOP; ++k) {
            int slot = atomicAdd(&counts[sel[k]], 1);
            if (slot < CAP) {
                rowtok[sel[k] * CAP + slot] = t;
                tokslot[t * K_TOP + k] = sel[k] * CAP + slot;
            } else {
                tokslot[t * K_TOP + k] = -1;
            }
            tokcoef[t * K_TOP + k] = wv[k] * inv;
        }
    }
}

// ------- gate+up GEMM fused (bf16, global_load_lds, double-buffered), h = silu(g)*u -------
__global__ __launch_bounds__(256) void gateup_kernel(
    const unsigned short* __restrict__ xbf,
    const unsigned short* __restrict__ gbf, const unsigned short* __restrict__ ubf,
    const int* __restrict__ counts, const int* __restrict__ rowtok,
    unsigned short* __restrict__ h_ws) {
    int bid = blockIdx.x;
    int e = bid / ((CAP / BM) * (I_DIM / BN));
    int rem = bid % ((CAP / BM) * (I_DIM / BN));
    int mt = rem / (I_DIM / BN);
    int nt = rem % (I_DIM / BN);
    int n_e = counts[e]; if (n_e > CAP) n_e = CAP;
    if (mt * BM >= n_e) return;

    __shared__ unsigned short As[2][BM * BK];   // ping-pong
    __shared__ unsigned short Bg[2][BM * BK];
    __shared__ unsigned short Bu[2][BM * BK];
    __shared__ int toks[BM];

    int tid = threadIdx.x, lane = tid & 63, wv = tid >> 6;
    if (tid < BM) {
        int r = mt * BM + tid;
        toks[tid] = (r < n_e) ? rowtok[e * CAP + r] : rowtok[e * CAP];
    }
    __syncthreads();

    int rA0 = (wv * 2 + 0) * 16 + (lane >> 2);
    int rA1 = rA0 + 16;
    int cst = (lane & 3) * 8;
    const unsigned short* gaA0 = xbf + (size_t)toks[rA0] * D_DIM + cst;
    const unsigned short* gaA1 = xbf + (size_t)toks[rA1] * D_DIM + cst;
    const unsigned short* gaG0 = gbf + ((size_t)e * I_DIM + nt * BN + rA0) * D_DIM + cst;
    const unsigned short* gaG1 = gbf + ((size_t)e * I_DIM + nt * BN + rA1) * D_DIM + cst;
    const unsigned short* gaU0 = ubf + ((size_t)e * I_DIM + nt * BN + rA0) * D_DIM + cst;
    const unsigned short* gaU1 = ubf + ((size_t)e * I_DIM + nt * BN + rA1) * D_DIM + cst;
    int l0 = (wv * 2 + 0) * 512;
    int l1 = (wv * 2 + 1) * 512;

    int wm = (wv >> 1) * 64;
    int wn = (wv & 1) * 64;

    f32x4 accg[4][4] = {};
    f32x4 accu[4][4] = {};

    // prologue: stage k=0 into parity 0
    gload16(gaA0, &As[0][l0]); gload16(gaA1, &As[0][l1]);
    gload16(gaG0, &Bg[0][l0]); gload16(gaG1, &Bg[0][l1]);
    gload16(gaU0, &Bu[0][l0]); gload16(gaU1, &Bu[0][l1]);

    for (int kk = 0; kk < D_DIM; kk += BK) {
        int p = (kk >> 5) & 1;
        __syncthreads();   // drains loads for parity p (issued previous iter)

        if (kk + BK < D_DIM) {   // prefetch next tile into parity p^1
            int q = p ^ 1, k2 = kk + BK;
            gload16(gaA0 + k2, &As[q][l0]); gload16(gaA1 + k2, &As[q][l1]);
            gload16(gaG0 + k2, &Bg[q][l0]); gload16(gaG1 + k2, &Bg[q][l1]);
            gload16(gaU0 + k2, &Bu[q][l0]); gload16(gaU1 + k2, &Bu[q][l1]);
        }

        s16x8 af[4], bgf[4], buf[4];
#pragma unroll
        for (int mi = 0; mi < 4; ++mi)
            af[mi] = *(const s16x8*)&As[p][(wm + mi * 16 + (lane & 15)) * BK + (lane >> 4) * 8];
#pragma unroll
        for (int ni = 0; ni < 4; ++ni) {
            bgf[ni] = *(const s16x8*)&Bg[p][(wn + ni * 16 + (lane & 15)) * BK + (lane >> 4) * 8];
            buf[ni] = *(const s16x8*)&Bu[p][(wn + ni * 16 + (lane & 15)) * BK + (lane >> 4) * 8];
        }
#pragma unroll
        for (int mi = 0; mi < 4; ++mi)
#pragma unroll
            for (int ni = 0; ni < 4; ++ni) {
                accg[mi][ni] = __builtin_amdgcn_mfma_f32_16x16x32_bf16(af[mi], bgf[ni], accg[mi][ni], 0, 0, 0);
                accu[mi][ni] = __builtin_amdgcn_mfma_f32_16x16x32_bf16(af[mi], buf[ni], accu[mi][ni], 0, 0, 0);
            }
    }

    int rq = (lane >> 4) * 4;
    int cq = lane & 15;
#pragma unroll
    for (int mi = 0; mi < 4; ++mi)
#pragma unroll
        for (int ni = 0; ni < 4; ++ni)
#pragma unroll
            for (int r = 0; r < 4; ++r) {
                int grow = mt * BM + wm + mi * 16 + rq + r;
                if (grow < n_e) {
                    float g = accg[mi][ni][r];
                    float hv = g / (1.0f + __expf(-g)) * accu[mi][ni][r];
                    int icol = nt * BN + wn + ni * 16 + cq;
                    h_ws[((size_t)e * CAP + grow) * I_DIM + icol] = f2bf(hv);
                }
            }
}

// ---------- down GEMM (bf16, global_load_lds, double-buffered) -> y_ws bf16 ----------
__global__ __launch_bounds__(256) void down_kernel(
    const unsigned short* __restrict__ h_ws, const unsigned short* __restrict__ dbf,
    const int* __restrict__ counts, unsigned short* __restrict__ y_ws) {
    int bid = blockIdx.x;
    int e = bid / ((CAP / BM) * (D_DIM / BN));
    int rem = bid % ((CAP / BM) * (D_DIM / BN));
    int mt = rem / (D_DIM / BN);
    int nt = rem % (D_DIM / BN);
    int n_e = counts[e]; if (n_e > CAP) n_e = CAP;
    if (mt * BM >= n_e) return;

    __shared__ unsigned short As[2][BM * BK];
    __shared__ unsigned short Bd[2][BM * BK];

    int tid = threadIdx.x, lane = tid & 63, wv = tid >> 6;

    int rA0 = (wv * 2 + 0) * 16 + (lane >> 2);
    int rA1 = rA0 + 16;
    int cst = (lane & 3) * 8;
    const unsigned short* gaA0 = h_ws + ((size_t)e * CAP + mt * BM + rA0) * I_DIM + cst;
    const unsigned short* gaA1 = h_ws + ((size_t)e * CAP + mt * BM + rA1) * I_DIM + cst;
    const unsigned short* gaB0 = dbf + ((size_t)e * D_DIM + nt * BN + rA0) * I_DIM + cst;
    const unsigned short* gaB1 = dbf + ((size_t)e * D_DIM + nt * BN + rA1) * I_DIM + cst;
    int l0 = (wv * 2 + 0) * 512;
    int l1 = (wv * 2 + 1) * 512;

    int wm = (wv >> 1) * 64;
    int wn = (wv & 1) * 64;

    f32x4 acc[4][4] = {};

    gload16(gaA0, &As[0][l0]); gload16(gaA1, &As[0][l1]);
    gload16(gaB0, &Bd[0][l0]); gload16(gaB1, &Bd[0][l1]);

    for (int kk = 0; kk < I_DIM; kk += BK) {
        int p = (kk >> 5) & 1;
        __syncthreads();

        if (kk + BK < I_DIM) {
            int q = p ^ 1, k2 = kk + BK;
            gload16(gaA0 + k2, &As[q][l0]); gload16(gaA1 + k2, &As[q][l1]);
            gload16(gaB0 + k2, &Bd[q][l0]); gload16(gaB1 + k2, &Bd[q][l1]);
        }

        s16x8 af[4], bf[4];
#pragma unroll
        for (int mi = 0; mi < 4; ++mi)
            af[mi] = *(const s16x8*)&As[p][(wm + mi * 16 + (lane & 15)) * BK + (lane >> 4) * 8];
#pragma unroll
        for (int ni = 0; ni < 4; ++ni)
            bf[ni] = *(const s16x8*)&Bd[p][(wn + ni * 16 + (lane & 15)) * BK + (lane >> 4) * 8];
#pragma unroll
        for (int mi = 0; mi < 4; ++mi)
#pragma unroll
            for (int ni = 0; ni < 4; ++ni)
                acc[mi][ni] = __builtin_amdgcn_mfma_f32_16x16x32_bf16(af[mi], bf[ni], acc[mi][ni], 0, 0, 0);
    }

    int rq = (lane >> 4) * 4;
    int cq = lane & 15;
#pragma unroll
    for (int mi = 0; mi < 4; ++mi)
#pragma unroll
        for (int ni = 0; ni < 4; ++ni)
#pragma unroll
            for (int r = 0; r < 4; ++r) {
                int grow = mt * BM + wm + mi * 16 + rq + r;
                if (grow < n_e) {
                    int dcol = nt * BN + wn + ni * 16 + cq;
                    y_ws[((size_t)e * CAP + grow) * D_DIM + dcol] = f2bf(acc[mi][ni][r]);
                }
            }
}

// ---------------- combine: out[t] = sum_k coef_k * y_ws[slot_k]  (one wave/token) ----------------
__global__ __launch_bounds__(256) void combine_kernel(
    const unsigned short* __restrict__ y_ws,
    const int* __restrict__ tokslot, const float* __restrict__ tokcoef,
    float* __restrict__ out) {
    int t = (blockIdx.x * 256 + threadIdx.x) >> 6;
    int lane = threadIdx.x & 63;
    float acc[16] = {};
#pragma unroll
    for (int k = 0; k < K_TOP; ++k) {
        int slot = tokslot[t * K_TOP + k];           // wave-uniform
        if (slot >= 0) {
            float c = tokcoef[t * K_TOP + k];
            const unsigned short* row = y_ws + (size_t)slot * D_DIM + lane * 16;
            s16x8 v0 = *(const s16x8*)row;
            s16x8 v1 = *(const s16x8*)(row + 8);
#pragma unroll
            for (int j = 0; j < 8; ++j) acc[j]     = fmaf(c, bf2f((unsigned short)v0[j]), acc[j]);
#pragma unroll
            for (int j = 0; j < 8; ++j) acc[8 + j] = fmaf(c, bf2f((unsigned short)v1[j]), acc[8 + j]);
        }
    }
    float* o = out + (size_t)t * D_DIM + lane * 16;
#pragma unroll
    for (int j = 0; j < 4; ++j)
        ((float4*)o)[j] = make_float4(acc[4 * j], acc[4 * j + 1], acc[4 * j + 2], acc[4 * j + 3]);
}

extern "C" void kernel_launch(void* const* d_in, const int* in_sizes, int n_in,
                              void* d_out, int out_size, void* d_ws, size_t ws_size,
                              hipStream_t stream) {
    const float* x  = (const float*)d_in[0];
    const float* rw = (const float*)d_in[1];
    const float* gw = (const float*)d_in[2];
    const float* uw = (const float*)d_in[3];
    const float* dw = (const float*)d_in[4];
    float* out = (float*)d_out;
    float* logits = out + (size_t)T_TOK * D_DIM;

    char* ws = (char*)d_ws;
    size_t off = 0;
    // region A (84 MB): xbf|gbf|ubf — dead after gateup; aliased by y_ws afterwards
    unsigned short* xbf = (unsigned short*)(ws + off); off += (size_t)T_TOK * D_DIM * 2;          // 16.78 MB
    unsigned short* gbf = (unsigned short*)(ws + off); off += (size_t)E_NUM * I_DIM * D_DIM * 2;  // 33.55 MB
    unsigned short* ubf = (unsigned short*)(ws + off); off += (size_t)E_NUM * I_DIM * D_DIM * 2;  // 33.55 MB
    unsigned short* y_ws = xbf;  // [E, CAP, D] bf16 = 83.89 MB, exactly region A
    unsigned short* dbf = (unsigned short*)(ws + off); off += (size_t)E_NUM * D_DIM * I_DIM * 2;  // 33.55 MB
    unsigned short* h_ws = (unsigned short*)(ws + off); off += (size_t)E_NUM * CAP * I_DIM * 2;   // 41.94 MB
    int* counts = (int*)(ws + off); off += 256;
    int* rowtok = (int*)(ws + off); off += (size_t)E_NUM * CAP * 4;
    int* tokslot = (int*)(ws + off); off += (size_t)T_TOK * K_TOP * 4;
    float* tokcoef = (float*)(ws + off); off += (size_t)T_TOK * K_TOP * 4;

    hipMemsetAsync(counts, 0, E_NUM * 4, stream);

    cvt_kernel<<<(int)((X_F4 + 3 * GW_F4) / 256), 256, 0, stream>>>(x, gw, uw, dw, xbf, gbf, ubf, dbf);
    router_kernel<<<T_TOK / 4, 256, 0, stream>>>(x, rw, logits);
    topk_kernel<<<T_TOK / 4, 256, 0, stream>>>(logits, counts, rowtok, tokslot, tokcoef);
    gateup_kernel<<<E_NUM * (CAP / BM) * (I_DIM / BN), 256, 0, stream>>>(xbf, gbf, ubf, counts, rowtok, h_ws);
    down_kernel<<<E_NUM * (CAP / BM) * (D_DIM / BN), 256, 0, stream>>>(h_ws, dbf, counts, y_ws);
    combine_kernel<<<T_TOK / 4, 256, 0, stream>>>(y_ws, tokslot, tokcoef, out);
}